// Round 2
// baseline (7999.016 us; speedup 1.0000x reference)
//
#include <hip/hip_runtime.h>
#include <hip/hip_bf16.h>

#define S_LEN 2048
#define DIM   768
#define NHEAD 12
#define HDIM  64
#define NBLK  32
#define BTOK  8192   // B * S
#define DFF_  3072

// ---------------- bb_mask normalization (handles bool-byte or int32/f32 layout)
__global__ void mask_norm_k(const unsigned char* __restrict__ p,
                            unsigned char* __restrict__ out) {
  int i = blockIdx.x * 256 + threadIdx.x;
  if (i < NBLK * NBLK) {
    // m[0][1] is always True. byte layout -> p[1]==1 ; int32/f32 layout -> p[1]==0
    bool byteLayout = (p[1] != 0);
    unsigned char v = byteLayout ? (unsigned char)(p[i] != 0)
                                 : (unsigned char)(((const int*)p)[i] != 0);
    out[i] = v;
  }
}

// ---------------- layernorm over D=768, one block (256 thr) per row ----------
__device__ __forceinline__ float blockReduceSum256(float v) {
  v += __shfl_down(v, 32); v += __shfl_down(v, 16); v += __shfl_down(v, 8);
  v += __shfl_down(v, 4);  v += __shfl_down(v, 2);  v += __shfl_down(v, 1);
  __shared__ float sm[4];
  int w = threadIdx.x >> 6;
  __syncthreads();
  if ((threadIdx.x & 63) == 0) sm[w] = v;
  __syncthreads();
  return sm[0] + sm[1] + sm[2] + sm[3];
}

__global__ __launch_bounds__(256) void ln_k(const float* __restrict__ x,
                                            const float* __restrict__ g,
                                            const float* __restrict__ b,
                                            float* __restrict__ y) {
  size_t row = blockIdx.x;
  const float* xr = x + row * DIM;
  int t = threadIdx.x;
  float v0 = xr[t], v1 = xr[t + 256], v2 = xr[t + 512];
  float tot = blockReduceSum256(v0 + v1 + v2);
  float mu = tot * (1.0f / DIM);
  float d0 = v0 - mu, d1 = v1 - mu, d2 = v2 - mu;
  float var = blockReduceSum256(d0 * d0 + d1 * d1 + d2 * d2) * (1.0f / DIM);
  float rstd = rsqrtf(var + 1e-5f);
  float* yr = y + row * DIM;
  yr[t]       = d0 * rstd * g[t]       + b[t];
  yr[t + 256] = d1 * rstd * g[t + 256] + b[t + 256];
  yr[t + 512] = d2 * rstd * g[t + 512] + b[t + 512];
}

// ---------------- f32 SGEMM: C[M,N] = A[M,K] @ B[K,N] (+bias)(+resid)(ReLU) --
// 128x128 tile, BK=8, 256 threads, 8x8 per thread. M,N,K all multiples of tile.
template<bool RELU, bool HASBIAS, bool HASRES>
__global__ __launch_bounds__(256) void gemm_k(
    const float* __restrict__ A, const float* __restrict__ B,
    const float* __restrict__ bias, const float* __restrict__ resid,
    float* __restrict__ Cout, int M, int N, int K) {
  __shared__ float As[8][128];
  __shared__ float Bs[8][128];
  int tid = threadIdx.x;
  int tx = tid & 15, ty = tid >> 4;
  int m0 = blockIdx.y * 128, n0 = blockIdx.x * 128;
  int arow = tid >> 1, akk = (tid & 1) * 4;
  int bkk  = tid >> 5, bcol = (tid & 31) * 4;
  const float* Ap = A + (size_t)(m0 + arow) * K + akk;
  const float* Bp = B + (size_t)bkk * N + n0 + bcol;
  float acc[8][8];
  #pragma unroll
  for (int i = 0; i < 8; ++i)
    #pragma unroll
    for (int j = 0; j < 8; ++j) acc[i][j] = 0.f;

  for (int k0 = 0; k0 < K; k0 += 8) {
    float4 av = *(const float4*)(Ap + k0);
    float4 bv = *(const float4*)(Bp + (size_t)k0 * N);
    __syncthreads();
    As[akk + 0][arow] = av.x; As[akk + 1][arow] = av.y;
    As[akk + 2][arow] = av.z; As[akk + 3][arow] = av.w;
    *(float4*)&Bs[bkk][bcol] = bv;
    __syncthreads();
    #pragma unroll
    for (int kk = 0; kk < 8; ++kk) {
      float a[8], b[8];
      #pragma unroll
      for (int i = 0; i < 8; ++i) a[i] = As[kk][ty * 8 + i];
      #pragma unroll
      for (int j = 0; j < 8; ++j) b[j] = Bs[kk][tx * 8 + j];
      #pragma unroll
      for (int i = 0; i < 8; ++i)
        #pragma unroll
        for (int j = 0; j < 8; ++j)
          acc[i][j] = fmaf(a[i], b[j], acc[i][j]);
    }
  }
  #pragma unroll
  for (int i = 0; i < 8; ++i) {
    int r = m0 + ty * 8 + i;
    #pragma unroll
    for (int j = 0; j < 8; ++j) {
      int c = n0 + tx * 8 + j;
      float v = acc[i][j];
      if (HASBIAS) v += bias[c];
      if (HASRES)  v += resid[(size_t)r * N + c];
      if (RELU)    v = fmaxf(v, 0.f);
      Cout[(size_t)r * N + c] = v;
    }
  }
}

// ---------------- block-sparse flash attention over 64x64 blocks ------------
// One workgroup per (q-block, head, batch). Online softmax. CAUSAL: only
// kb<=qb, with intra-block triangular mask on the diagonal block.
template<bool CAUSAL>
__global__ __launch_bounds__(256) void bb_attn_k(
    const float* __restrict__ Q, const float* __restrict__ K,
    const float* __restrict__ V, float* __restrict__ O,
    const unsigned char* __restrict__ mask) {
  __shared__ float Qs[64][65];
  __shared__ float KVs[64][65];
  __shared__ float Ps[64][65];
  int qb = blockIdx.x, h = blockIdx.y, b = blockIdx.z;
  int t = threadIdx.x;
  size_t qbase = ((size_t)b * S_LEN + (size_t)qb * 64) * DIM + h * HDIM;
  #pragma unroll
  for (int i = 0; i < 4; ++i) {
    int e = t + 256 * i;
    int r = e >> 4, d4 = (e & 15) << 2;
    float4 qv = *(const float4*)(Q + qbase + (size_t)r * DIM + d4);
    Qs[r][d4 + 0] = qv.x * 0.125f; Qs[r][d4 + 1] = qv.y * 0.125f;
    Qs[r][d4 + 2] = qv.z * 0.125f; Qs[r][d4 + 3] = qv.w * 0.125f;
  }
  int r = t >> 2, cg = t & 3;           // row 0..63, col-group 0..3 (16 cols each)
  float m = -3.0e38f, l = 0.f;
  float acc[16];
  #pragma unroll
  for (int j = 0; j < 16; ++j) acc[j] = 0.f;
  __syncthreads();

  int kbEnd = CAUSAL ? (qb + 1) : NBLK;
  for (int kb = 0; kb < kbEnd; ++kb) {
    if (!mask[qb * NBLK + kb]) continue;
    size_t kbase = ((size_t)b * S_LEN + (size_t)kb * 64) * DIM + h * HDIM;
    #pragma unroll
    for (int i = 0; i < 4; ++i) {
      int e = t + 256 * i;
      int rr = e >> 4, d4 = (e & 15) << 2;
      float4 kv = *(const float4*)(K + kbase + (size_t)rr * DIM + d4);
      KVs[rr][d4 + 0] = kv.x; KVs[rr][d4 + 1] = kv.y;
      KVs[rr][d4 + 2] = kv.z; KVs[rr][d4 + 3] = kv.w;
    }
    __syncthreads();
    float sv[16];
    #pragma unroll
    for (int j = 0; j < 16; ++j) sv[j] = 0.f;
    for (int d = 0; d < 64; ++d) {
      float qd = Qs[r][d];
      #pragma unroll
      for (int j = 0; j < 16; ++j)
        sv[j] = fmaf(qd, KVs[cg * 16 + j][d], sv[j]);
    }
    if (CAUSAL && kb == qb) {
      #pragma unroll
      for (int j = 0; j < 16; ++j)
        if (cg * 16 + j > r) sv[j] = -1e9f;
    }
    float mx = sv[0];
    #pragma unroll
    for (int j = 1; j < 16; ++j) mx = fmaxf(mx, sv[j]);
    mx = fmaxf(mx, __shfl_xor(mx, 1));
    mx = fmaxf(mx, __shfl_xor(mx, 2));
    float newm = fmaxf(m, mx);
    float corr = expf(m - newm);
    float rs = 0.f;
    #pragma unroll
    for (int j = 0; j < 16; ++j) {
      float p = expf(sv[j] - newm);
      Ps[r][cg * 16 + j] = p;
      rs += p;
    }
    rs += __shfl_xor(rs, 1);
    rs += __shfl_xor(rs, 2);
    l = l * corr + rs;
    m = newm;
    #pragma unroll
    for (int j = 0; j < 16; ++j) acc[j] *= corr;
    __syncthreads();                      // Ps visible; done reading K from KVs
    #pragma unroll
    for (int i = 0; i < 4; ++i) {
      int e = t + 256 * i;
      int rr = e >> 4, d4 = (e & 15) << 2;
      float4 vv = *(const float4*)(V + kbase + (size_t)rr * DIM + d4);
      KVs[rr][d4 + 0] = vv.x; KVs[rr][d4 + 1] = vv.y;
      KVs[rr][d4 + 2] = vv.z; KVs[rr][d4 + 3] = vv.w;
    }
    __syncthreads();
    for (int c = 0; c < 64; ++c) {
      float p = Ps[r][c];
      #pragma unroll
      for (int j = 0; j < 16; ++j)
        acc[j] = fmaf(p, KVs[c][cg * 16 + j], acc[j]);
    }
    __syncthreads();                      // protect Ps/KVs for next iteration
  }
  float inv = 1.0f / fmaxf(l, 1e-30f);
  size_t obase = ((size_t)b * S_LEN + (size_t)qb * 64 + r) * DIM + h * HDIM + cg * 16;
  #pragma unroll
  for (int j = 0; j < 16; ++j)
    O[obase + j] = acc[j] * inv;
}

extern "C" void kernel_launch(void* const* d_in, const int* in_sizes, int n_in,
                              void* d_out, int out_size, void* d_ws, size_t ws_size,
                              hipStream_t stream) {
  const float* q    = (const float*)d_in[0];
  const float* enc  = (const float*)d_in[1];
  const unsigned char* bbm = (const unsigned char*)d_in[2];
  const float* Wq_s = (const float*)d_in[3];
  const float* Wk_s = (const float*)d_in[4];
  const float* Wv_s = (const float*)d_in[5];
  const float* Wo_s = (const float*)d_in[6];
  const float* Wq_c = (const float*)d_in[7];
  const float* Wk_c = (const float*)d_in[8];
  const float* Wv_c = (const float*)d_in[9];
  const float* Wo_c = (const float*)d_in[10];
  const float* ln_g = (const float*)d_in[11];
  const float* ln_b = (const float*)d_in[12];
  const float* W1   = (const float*)d_in[13];
  const float* b1   = (const float*)d_in[14];
  const float* W2   = (const float*)d_in[15];
  const float* b2   = (const float*)d_in[16];

  unsigned char* wsb   = (unsigned char*)d_ws;
  unsigned char* maskn = wsb;                       // 1024 B used
  float* f = (float*)(wsb + 4096);
  const size_t NM = (size_t)BTOK * DIM;
  float* A  = f;            // LN output
  float* Bq = f + NM;       // Q proj
  float* Bk = f + 2 * NM;   // K proj
  float* Bv = f + 3 * NM;   // V proj
  float* Cc = f + 4 * NM;   // attention context
  float* X  = f + 5 * NM;   // running residual
  float* F  = Bq;           // FFN hidden [8192,3072] aliases Bq..Cc (dead then)

  dim3 blk(256);
  dim3 g768(768 / 128, BTOK / 128);
  dim3 gff1(DFF_ / 128, BTOK / 128);
  dim3 ga(NBLK, NHEAD, 4);

  mask_norm_k<<<4, blk, 0, stream>>>(bbm, maskn);

  // ---- self attention ----
  ln_k<<<BTOK, blk, 0, stream>>>(q, ln_g, ln_b, A);
  gemm_k<false,false,false><<<g768, blk, 0, stream>>>(A, Wq_s, nullptr, nullptr, Bq, BTOK, 768, 768);
  gemm_k<false,false,false><<<g768, blk, 0, stream>>>(A, Wk_s, nullptr, nullptr, Bk, BTOK, 768, 768);
  gemm_k<false,false,false><<<g768, blk, 0, stream>>>(A, Wv_s, nullptr, nullptr, Bv, BTOK, 768, 768);
  bb_attn_k<true><<<ga, blk, 0, stream>>>(Bq, Bk, Bv, Cc, maskn);
  gemm_k<false,false,true><<<g768, blk, 0, stream>>>(Cc, Wo_s, nullptr, q, X, BTOK, 768, 768);

  // ---- cross attention (KV from raw encoder_out) ----
  ln_k<<<BTOK, blk, 0, stream>>>(X, ln_g, ln_b, A);
  gemm_k<false,false,false><<<g768, blk, 0, stream>>>(A,   Wq_c, nullptr, nullptr, Bq, BTOK, 768, 768);
  gemm_k<false,false,false><<<g768, blk, 0, stream>>>(enc, Wk_c, nullptr, nullptr, Bk, BTOK, 768, 768);
  gemm_k<false,false,false><<<g768, blk, 0, stream>>>(enc, Wv_c, nullptr, nullptr, Bv, BTOK, 768, 768);
  bb_attn_k<false><<<ga, blk, 0, stream>>>(Bq, Bk, Bv, Cc, maskn);
  gemm_k<false,false,true><<<g768, blk, 0, stream>>>(Cc, Wo_c, nullptr, X, X, BTOK, 768, 768);

  // ---- FFN ----
  ln_k<<<BTOK, blk, 0, stream>>>(X, ln_g, ln_b, A);
  gemm_k<true,true,false><<<gff1, blk, 0, stream>>>(A, W1, b1, nullptr, F, BTOK, DFF_, 768);
  gemm_k<false,true,true><<<g768, blk, 0, stream>>>(F, W2, b2, X, (float*)d_out, BTOK, 768, DFF_);

  (void)in_sizes; (void)n_in; (void)out_size; (void)ws_size;
}

// Round 3
// 893.644 us; speedup vs baseline: 8.9510x; 8.9510x over previous
//
#include <hip/hip_runtime.h>
#include <hip/hip_bf16.h>

#define S_LEN 2048
#define DIM   768
#define NHEAD 12
#define HDIM  64
#define NBLK  32
#define BTOK  8192   // B * S
#define DFF_  3072

typedef __attribute__((ext_vector_type(8))) short bf16x8;
typedef __attribute__((ext_vector_type(4))) float f32x4;

__device__ __forceinline__ void glds16(const void* g, void* l) {
  __builtin_amdgcn_global_load_lds(
      (const __attribute__((address_space(1))) void*)g,
      (__attribute__((address_space(3))) void*)l, 16, 0, 0);
}

__device__ __forceinline__ unsigned short bfbits(float f) {
  __hip_bfloat16 t = __float2bfloat16(f);
  return *(unsigned short*)&t;
}

// ---------------- bb_mask normalization (bool-byte or int32 layout) ---------
__global__ void mask_norm_k(const unsigned char* __restrict__ p,
                            unsigned char* __restrict__ out) {
  int i = blockIdx.x * 256 + threadIdx.x;
  if (i < NBLK * NBLK) {
    bool byteLayout = (p[1] != 0);   // m[0][1] always true
    out[i] = byteLayout ? (unsigned char)(p[i] != 0)
                        : (unsigned char)(((const int*)p)[i] != 0);
  }
}

// ---------------- layernorm: f32 in -> bf16 out, one block per row ----------
__device__ __forceinline__ float blockReduceSum256(float v) {
  v += __shfl_down(v, 32); v += __shfl_down(v, 16); v += __shfl_down(v, 8);
  v += __shfl_down(v, 4);  v += __shfl_down(v, 2);  v += __shfl_down(v, 1);
  __shared__ float sm[4];
  int w = threadIdx.x >> 6;
  __syncthreads();
  if ((threadIdx.x & 63) == 0) sm[w] = v;
  __syncthreads();
  return sm[0] + sm[1] + sm[2] + sm[3];
}

__global__ __launch_bounds__(256) void ln_k(const float* __restrict__ x,
                                            const float* __restrict__ g,
                                            const float* __restrict__ b,
                                            __hip_bfloat16* __restrict__ y) {
  size_t row = blockIdx.x;
  const float* xr = x + row * DIM;
  int t = threadIdx.x;
  float v0 = xr[t], v1 = xr[t + 256], v2 = xr[t + 512];
  float tot = blockReduceSum256(v0 + v1 + v2);
  float mu = tot * (1.0f / DIM);
  float d0 = v0 - mu, d1 = v1 - mu, d2 = v2 - mu;
  float var = blockReduceSum256(d0 * d0 + d1 * d1 + d2 * d2) * (1.0f / DIM);
  float rstd = rsqrtf(var + 1e-5f);
  __hip_bfloat16* yr = y + row * DIM;
  yr[t]       = __float2bfloat16(d0 * rstd * g[t]       + b[t]);
  yr[t + 256] = __float2bfloat16(d1 * rstd * g[t + 256] + b[t + 256]);
  yr[t + 512] = __float2bfloat16(d2 * rstd * g[t + 512] + b[t + 512]);
}

// ---------------- elementwise f32 -> bf16 cast ------------------------------
__global__ __launch_bounds__(256) void castbf_k(const float* __restrict__ x,
                                                __hip_bfloat16* __restrict__ y,
                                                int n) {
  int i = (blockIdx.x * 256 + threadIdx.x) * 8;
  if (i < n) {
    float4 v0 = *(const float4*)(x + i);
    float4 v1 = *(const float4*)(x + i + 4);
    union { bf16x8 v; unsigned short u[8]; } pk;
    pk.u[0] = bfbits(v0.x); pk.u[1] = bfbits(v0.y);
    pk.u[2] = bfbits(v0.z); pk.u[3] = bfbits(v0.w);
    pk.u[4] = bfbits(v1.x); pk.u[5] = bfbits(v1.y);
    pk.u[6] = bfbits(v1.z); pk.u[7] = bfbits(v1.w);
    *(bf16x8*)((unsigned short*)y + i) = pk.v;
  }
}

// ---------------- weight transpose+cast: W[R][C] f32 -> Wt[C][R] bf16 -------
__global__ __launch_bounds__(256) void tcast_k(const float* __restrict__ W,
                                               __hip_bfloat16* __restrict__ Wt,
                                               int R, int C) {
  __shared__ float T[64][65];
  int r0 = blockIdx.y * 64, c0 = blockIdx.x * 64;
  int t = threadIdx.x;
  int r = t >> 2, cg = (t & 3) * 16;
  #pragma unroll
  for (int ii = 0; ii < 16; ii += 4) {
    float4 v = *(const float4*)(W + (size_t)(r0 + r) * C + c0 + cg + ii);
    T[r][cg + ii + 0] = v.x; T[r][cg + ii + 1] = v.y;
    T[r][cg + ii + 2] = v.z; T[r][cg + ii + 3] = v.w;
  }
  __syncthreads();
  int oc = t >> 2, og = (t & 3) * 16;
  union { bf16x8 v; unsigned short u[8]; } p0, p1;
  #pragma unroll
  for (int ii = 0; ii < 8; ++ii) p0.u[ii] = bfbits(T[og + ii][oc]);
  #pragma unroll
  for (int ii = 0; ii < 8; ++ii) p1.u[ii] = bfbits(T[og + 8 + ii][oc]);
  unsigned short* dst = (unsigned short*)Wt + (size_t)(c0 + oc) * R + r0 + og;
  *(bf16x8*)dst = p0.v;
  *(bf16x8*)(dst + 8) = p1.v;
}

// ---------------- bf16 MFMA GEMM: C[M,N] = A[M,K] @ Bt[N,K]^T ---------------
// 128x128 tile, BK=64, 4 waves (2x2 of 64x64), XOR-swizzled LDS (T2/rule 21:
// inverse swizzle applied on global source, same swizzle on ds_read).
template<bool BF16OUT, bool HASBIAS, bool HASRES, bool RELU, bool TRANSV>
__global__ __launch_bounds__(256) void mgemm_k(
    const __hip_bfloat16* __restrict__ A,   // [M][K] bf16
    const __hip_bfloat16* __restrict__ Bt,  // [N][K] bf16
    const float* __restrict__ bias,
    const float* __restrict__ resid,        // f32 [M][N]
    void* __restrict__ Cout,
    int M, int N, int K) {
  __shared__ char Asl[128 * 128];   // 128 rows x 64 bf16
  __shared__ char Bsl[128 * 128];
  int tid = threadIdx.x, w = tid >> 6, lane = tid & 63;
  int g = lane >> 4, cc = lane & 15;
  int wr = w >> 1, wc = w & 1;
  int m0 = blockIdx.y * 128, n0 = blockIdx.x * 128;

  f32x4 acc[4][4];
  #pragma unroll
  for (int i = 0; i < 4; ++i)
    #pragma unroll
    for (int j = 0; j < 4; ++j) acc[i][j] = (f32x4){0.f, 0.f, 0.f, 0.f};

  for (int k0 = 0; k0 < K; k0 += 64) {
    __syncthreads();
    #pragma unroll
    for (int ii = 0; ii < 4; ++ii) {
      int chunk = ii * 256 + w * 64 + lane;
      int row = chunk >> 3, hh = chunk & 7;
      int koff = k0 + ((hh ^ (row & 7)) << 3);
      glds16(A  + (size_t)(m0 + row) * K + koff, Asl + (ii * 256 + w * 64) * 16);
      glds16(Bt + (size_t)(n0 + row) * K + koff, Bsl + (ii * 256 + w * 64) * 16);
    }
    __syncthreads();   // compiler drains vmcnt before s_barrier
    bf16x8 a[4][2], b[4][2];
    #pragma unroll
    for (int i = 0; i < 4; ++i)
      #pragma unroll
      for (int s = 0; s < 2; ++s) {
        int row = wr * 64 + i * 16 + cc;
        a[i][s] = *(const bf16x8*)(Asl + row * 128 + (((s * 4 + g) ^ (cc & 7)) << 4));
      }
    #pragma unroll
    for (int j = 0; j < 4; ++j)
      #pragma unroll
      for (int s = 0; s < 2; ++s) {
        int row = wc * 64 + j * 16 + cc;
        b[j][s] = *(const bf16x8*)(Bsl + row * 128 + (((s * 4 + g) ^ (cc & 7)) << 4));
      }
    #pragma unroll
    for (int i = 0; i < 4; ++i)
      #pragma unroll
      for (int j = 0; j < 4; ++j)
        #pragma unroll
        for (int s = 0; s < 2; ++s)
          acc[i][j] = __builtin_amdgcn_mfma_f32_16x16x32_bf16(a[i][s], b[j][s], acc[i][j], 0, 0, 0);
  }
  #pragma unroll
  for (int i = 0; i < 4; ++i)
    #pragma unroll
    for (int j = 0; j < 4; ++j)
      #pragma unroll
      for (int e = 0; e < 4; ++e) {
        int r   = m0 + wr * 64 + i * 16 + g * 4 + e;
        int col = n0 + wc * 64 + j * 16 + cc;
        float v = acc[i][j][e];
        if (HASBIAS) v += bias[col];
        if (HASRES)  v += resid[(size_t)r * N + col];
        if (RELU)    v = fmaxf(v, 0.f);
        if (TRANSV) {
          int bb = r >> 11, s = r & 2047;   // Vt[b][col][s]
          ((__hip_bfloat16*)Cout)[(size_t)bb * DIM * S_LEN + (size_t)col * S_LEN + s] = __float2bfloat16(v);
        } else if (BF16OUT) {
          ((__hip_bfloat16*)Cout)[(size_t)r * N + col] = __float2bfloat16(v);
        } else {
          ((float*)Cout)[(size_t)r * N + col] = v;
        }
      }
}

// ---------------- block-sparse MFMA flash attention -------------------------
// grid (qb, head, batch), 256 thr = 4 waves x 16 q-rows. Q hoisted to regs;
// K swizzled in LDS; V staged pre-transposed (Vt[b][d][s]); P via per-wave
// swizzled LDS tile; online softmax in registers (C/D row = (l>>4)*4+e).
template<bool CAUSAL>
__global__ __launch_bounds__(256) void mattn_k(
    const __hip_bfloat16* __restrict__ Qg,   // [B*S][768]
    const __hip_bfloat16* __restrict__ Kg,   // [B*S][768]
    const __hip_bfloat16* __restrict__ Vtg,  // [B][768][2048]
    __hip_bfloat16* __restrict__ O,          // [B*S][768]
    const unsigned char* __restrict__ mask) {
  __shared__ char Qs[8192], Ks[8192], Vs[8192], Ps[8192];
  int qb = blockIdx.x, h = blockIdx.y, b = blockIdx.z;
  int t = threadIdx.x, w = t >> 6, lane = t & 63;
  int g = lane >> 4, cc = lane & 15;

  #pragma unroll
  for (int ii = 0; ii < 2; ++ii) {
    int chunk = ii * 256 + w * 64 + lane;
    int qr = chunk >> 3, hh = chunk & 7;
    glds16(Qg + (size_t)(b * S_LEN + qb * 64 + qr) * DIM + h * HDIM + ((hh ^ (qr & 7)) << 3),
           Qs + (ii * 256 + w * 64) * 16);
  }
  __syncthreads();
  bf16x8 aq[2];
  #pragma unroll
  for (int s = 0; s < 2; ++s) {
    int row = w * 16 + cc;
    aq[s] = *(const bf16x8*)(Qs + row * 128 + (((s * 4 + g) ^ (cc & 7)) << 4));
  }

  float m_[4], l_[4];
  f32x4 accO[4];
  #pragma unroll
  for (int e = 0; e < 4; ++e) { m_[e] = -3.0e38f; l_[e] = 0.f; }
  #pragma unroll
  for (int j = 0; j < 4; ++j) accO[j] = (f32x4){0.f, 0.f, 0.f, 0.f};

  int kbEnd = CAUSAL ? (qb + 1) : NBLK;
  for (int kb = 0; kb < kbEnd; ++kb) {
    if (!mask[qb * NBLK + kb]) continue;
    __syncthreads();   // prev-iter reads of Ks/Vs done
    #pragma unroll
    for (int ii = 0; ii < 2; ++ii) {
      int chunk = ii * 256 + w * 64 + lane;
      int rr = chunk >> 3, hh = chunk & 7;
      glds16(Kg + (size_t)(b * S_LEN + kb * 64 + rr) * DIM + h * HDIM + ((hh ^ (rr & 7)) << 3),
             Ks + (ii * 256 + w * 64) * 16);
      glds16(Vtg + (size_t)b * DIM * S_LEN + (size_t)(h * HDIM + rr) * S_LEN + kb * 64 + ((hh ^ (rr & 7)) << 3),
             Vs + (ii * 256 + w * 64) * 16);
    }
    __syncthreads();

    f32x4 S[4];
    #pragma unroll
    for (int j = 0; j < 4; ++j) S[j] = (f32x4){0.f, 0.f, 0.f, 0.f};
    #pragma unroll
    for (int j = 0; j < 4; ++j)
      #pragma unroll
      for (int s = 0; s < 2; ++s) {
        int kv = j * 16 + cc;
        bf16x8 bk = *(const bf16x8*)(Ks + kv * 128 + (((s * 4 + g) ^ (cc & 7)) << 4));
        S[j] = __builtin_amdgcn_mfma_f32_16x16x32_bf16(aq[s], bk, S[j], 0, 0, 0);
      }

    float p_[4][4];   // [j][e]
    #pragma unroll
    for (int e = 0; e < 4; ++e) {
      float mm = -3.0e38f;
      #pragma unroll
      for (int j = 0; j < 4; ++j) {
        float sv = S[j][e] * 0.125f;
        if (CAUSAL && kb == qb) {
          int ql = w * 16 + g * 4 + e, kl = j * 16 + cc;
          if (kl > ql) sv = -1e9f;
        }
        p_[j][e] = sv;
        mm = fmaxf(mm, sv);
      }
      mm = fmaxf(mm, __shfl_xor(mm, 1));
      mm = fmaxf(mm, __shfl_xor(mm, 2));
      mm = fmaxf(mm, __shfl_xor(mm, 4));
      mm = fmaxf(mm, __shfl_xor(mm, 8));
      float newm = fmaxf(m_[e], mm);
      float corr = expf(m_[e] - newm);
      float rs = 0.f;
      #pragma unroll
      for (int j = 0; j < 4; ++j) {
        float p = expf(p_[j][e] - newm);
        p_[j][e] = p;
        rs += p;
      }
      rs += __shfl_xor(rs, 1); rs += __shfl_xor(rs, 2);
      rs += __shfl_xor(rs, 4); rs += __shfl_xor(rs, 8);
      l_[e] = l_[e] * corr + rs;
      m_[e] = newm;
      #pragma unroll
      for (int j = 0; j < 4; ++j) accO[j][e] *= corr;
      int ql = g * 4 + e;
      #pragma unroll
      for (int j = 0; j < 4; ++j) {
        int kv = j * 16 + cc;
        int byt = w * 2048 + ql * 128 + ((((kv >> 3) ^ (ql & 7))) << 4) + ((kv & 7) << 1);
        *(unsigned short*)(Ps + byt) = bfbits(p_[j][e]);
      }
    }
    #pragma unroll
    for (int s = 0; s < 2; ++s) {
      bf16x8 ap = *(const bf16x8*)(Ps + w * 2048 + cc * 128 + (((s * 4 + g) ^ (cc & 7)) << 4));
      #pragma unroll
      for (int j = 0; j < 4; ++j) {
        int d = j * 16 + cc;
        bf16x8 bv = *(const bf16x8*)(Vs + d * 128 + (((s * 4 + g) ^ (cc & 7)) << 4));
        accO[j] = __builtin_amdgcn_mfma_f32_16x16x32_bf16(ap, bv, accO[j], 0, 0, 0);
      }
    }
  }
  #pragma unroll
  for (int e = 0; e < 4; ++e) {
    float inv = 1.0f / fmaxf(l_[e], 1e-30f);
    int tok = b * S_LEN + qb * 64 + w * 16 + g * 4 + e;
    #pragma unroll
    for (int j = 0; j < 4; ++j)
      O[(size_t)tok * DIM + h * HDIM + j * 16 + cc] = __float2bfloat16(accO[j][e] * inv);
  }
}

extern "C" void kernel_launch(void* const* d_in, const int* in_sizes, int n_in,
                              void* d_out, int out_size, void* d_ws, size_t ws_size,
                              hipStream_t stream) {
  const float* q    = (const float*)d_in[0];
  const float* enc  = (const float*)d_in[1];
  const unsigned char* bbm = (const unsigned char*)d_in[2];
  const float* Wsrc[8] = {(const float*)d_in[3], (const float*)d_in[4],
                          (const float*)d_in[5], (const float*)d_in[6],
                          (const float*)d_in[7], (const float*)d_in[8],
                          (const float*)d_in[9], (const float*)d_in[10]};
  const float* ln_g = (const float*)d_in[11];
  const float* ln_b = (const float*)d_in[12];
  const float* W1   = (const float*)d_in[13];
  const float* b1   = (const float*)d_in[14];
  const float* W2   = (const float*)d_in[15];
  const float* b2   = (const float*)d_in[16];

  char* ws = (char*)d_ws;
  unsigned char* maskn = (unsigned char*)ws;
  const size_t WT1 = (size_t)DIM * DIM * 2;      // 1,179,648
  __hip_bfloat16* Wt[8];
  for (int i = 0; i < 8; ++i) Wt[i] = (__hip_bfloat16*)(ws + 4096 + i * WT1);
  __hip_bfloat16* W1t  = (__hip_bfloat16*)(ws + 9441280);
  __hip_bfloat16* W2t  = (__hip_bfloat16*)(ws + 14159872);
  __hip_bfloat16* Ebf  = (__hip_bfloat16*)(ws + 18878464);
  float*          X    = (float*)         (ws + 31461376);
  __hip_bfloat16* Abf  = (__hip_bfloat16*)(ws + 56627200);
  __hip_bfloat16* Bq   = (__hip_bfloat16*)(ws + 69210112);
  __hip_bfloat16* Bk   = (__hip_bfloat16*)(ws + 81793024);
  __hip_bfloat16* Vt   = (__hip_bfloat16*)(ws + 94375936);
  __hip_bfloat16* Cc   = (__hip_bfloat16*)(ws + 106958848);
  __hip_bfloat16* F    = Bq;   // [8192][3072] aliases Bq..Cc (dead in FFN phase)

  dim3 blk(256);
  dim3 gsq(12, 12), gw1(48, 12), gw2(12, 48);
  dim3 g768(6, 64), gff(24, 64);
  dim3 ga(NBLK, NHEAD, 4);

  mask_norm_k<<<4, blk, 0, stream>>>(bbm, maskn);
  for (int i = 0; i < 8; ++i)
    tcast_k<<<gsq, blk, 0, stream>>>(Wsrc[i], Wt[i], DIM, DIM);
  tcast_k<<<gw1, blk, 0, stream>>>(W1, W1t, DIM, DFF_);
  tcast_k<<<gw2, blk, 0, stream>>>(W2, W2t, DFF_, DIM);
  castbf_k<<<3072, blk, 0, stream>>>(enc, Ebf, BTOK * DIM);

  // ---- self attention ----
  ln_k<<<BTOK, blk, 0, stream>>>(q, ln_g, ln_b, Abf);
  mgemm_k<true,false,false,false,false><<<g768, blk, 0, stream>>>(Abf, Wt[0], nullptr, nullptr, Bq, BTOK, DIM, DIM);
  mgemm_k<true,false,false,false,false><<<g768, blk, 0, stream>>>(Abf, Wt[1], nullptr, nullptr, Bk, BTOK, DIM, DIM);
  mgemm_k<true,false,false,false,true ><<<g768, blk, 0, stream>>>(Abf, Wt[2], nullptr, nullptr, Vt, BTOK, DIM, DIM);
  mattn_k<true><<<ga, blk, 0, stream>>>(Bq, Bk, Vt, Cc, maskn);
  mgemm_k<false,false,true,false,false><<<g768, blk, 0, stream>>>(Cc, Wt[3], nullptr, q, X, BTOK, DIM, DIM);

  // ---- cross attention (KV from raw encoder_out) ----
  ln_k<<<BTOK, blk, 0, stream>>>(X, ln_g, ln_b, Abf);
  mgemm_k<true,false,false,false,false><<<g768, blk, 0, stream>>>(Abf, Wt[4], nullptr, nullptr, Bq, BTOK, DIM, DIM);
  mgemm_k<true,false,false,false,false><<<g768, blk, 0, stream>>>(Ebf, Wt[5], nullptr, nullptr, Bk, BTOK, DIM, DIM);
  mgemm_k<true,false,false,false,true ><<<g768, blk, 0, stream>>>(Ebf, Wt[6], nullptr, nullptr, Vt, BTOK, DIM, DIM);
  mattn_k<false><<<ga, blk, 0, stream>>>(Bq, Bk, Vt, Cc, maskn);
  mgemm_k<false,false,true,false,false><<<g768, blk, 0, stream>>>(Cc, Wt[7], nullptr, X, X, BTOK, DIM, DIM);

  // ---- FFN ----
  ln_k<<<BTOK, blk, 0, stream>>>(X, ln_g, ln_b, Abf);
  mgemm_k<true,true,false,true,false><<<gff, blk, 0, stream>>>(Abf, W1t, b1, nullptr, F, BTOK, DFF_, DIM);
  mgemm_k<false,true,true,false,false><<<g768, blk, 0, stream>>>(F, W2t, b2, X, d_out, BTOK, DIM, DFF_);

  (void)in_sizes; (void)n_in; (void)out_size; (void)ws_size;
}